// Round 8
// baseline (315.246 us; speedup 1.0000x reference)
//
#include <hip/hip_runtime.h>
#include <hip/hip_bf16.h>
#include <stdint.h>
#include <math.h>

typedef __bf16 bf16;
typedef bf16 bf16x8 __attribute__((ext_vector_type(8)));
typedef bf16 bf16x4 __attribute__((ext_vector_type(4)));
typedef float f32x4 __attribute__((ext_vector_type(4)));
typedef unsigned int u32;

#define TOKENS 8192
#define HD 512
#define NE 8
#define IM 1024
#define ISH 2048
#define CAP 2560   // per-expert slot capacity; mean load 2048, sigma~42

__device__ __forceinline__ void gld16(const void* g, void* l) {
  __builtin_amdgcn_global_load_lds(
      (const __attribute__((address_space(1))) u32*)g,
      (__attribute__((address_space(3))) u32*)l, 16, 0, 0);
}

// ---------------- fused router + weight-convert (one dispatch) ----------------
#define RT_BLOCKS (TOKENS / 4)
#define CVT_BLOCKS 3840
#define CVT_STRIDE (CVT_BLOCKS * 256)   // F4_TOT = 4 * CVT_STRIDE exactly
#define F4_E  (NE * IM * HD / 4)
#define F4_S  (ISH * HD / 4)
#define F4_C1 (F4_E)
#define F4_C2 (F4_C1 + F4_E)
#define F4_C3 (F4_C2 + F4_S)
#define F4_C4 (F4_C3 + F4_S)
#define F4_C5 (F4_C4 + F4_E)
#define F4_TOT (F4_C5 + F4_S)

__launch_bounds__(256)
__global__ void router_cvt_k(const float* __restrict__ x, const float* __restrict__ gw,
                             const float* __restrict__ sgw, float* __restrict__ logits,
                             float* __restrict__ sgate, int* __restrict__ topi,
                             float* __restrict__ topw, int* __restrict__ counts,
                             bf16* __restrict__ xb,
                             const float* __restrict__ e1, const float* __restrict__ e3,
                             const float* __restrict__ s1, const float* __restrict__ s3,
                             const float* __restrict__ e2, const float* __restrict__ s2,
                             bf16* __restrict__ wdst) {
  if (blockIdx.x >= RT_BLOCKS) {
    int idx = (blockIdx.x - RT_BLOCKS) * 256 + threadIdx.x;
#pragma unroll
    for (int it = 0; it < 4; it++, idx += CVT_STRIDE) {
      const float* s; int off;
      if (idx < F4_C1)      { s = e1; off = idx; }
      else if (idx < F4_C2) { s = e3; off = idx - F4_C1; }
      else if (idx < F4_C3) { s = s1; off = idx - F4_C2; }
      else if (idx < F4_C4) { s = s3; off = idx - F4_C3; }
      else if (idx < F4_C5) { s = e2; off = idx - F4_C4; }
      else                  { s = s2; off = idx - F4_C5; }
      const float4 v = ((const float4*)s)[off];
      bf16x4 o;
      o.x = (bf16)v.x; o.y = (bf16)v.y; o.z = (bf16)v.z; o.w = (bf16)v.w;
      ((bf16x4*)wdst)[idx] = o;
    }
    return;
  }
  if (blockIdx.x == 0 && threadIdx.x < NE) counts[threadIdx.x] = 0;
  __shared__ float gws[9][512];
  for (int i = threadIdx.x; i < 9 * 512; i += 256) {
    int r = i >> 9, c = i & 511;
    float v = (r < 8) ? gw[i] : sgw[c];
    gws[r][((c & 7) << 6) | (c >> 3)] = v;
  }
  __syncthreads();
  int wave = threadIdx.x >> 6, lane = threadIdx.x & 63;
  int t = blockIdx.x * 4 + wave;
  const float* xp = x + (size_t)t * HD + lane * 8;
  float4 va = *(const float4*)xp;
  float4 vb = *(const float4*)(xp + 4);
  float xv[8] = {va.x, va.y, va.z, va.w, vb.x, vb.y, vb.z, vb.w};
  {
    bf16x8 xo;
#pragma unroll
    for (int j = 0; j < 8; j++) xo[j] = (bf16)xv[j];
    *(bf16x8*)(xb + (size_t)t * HD + lane * 8) = xo;
  }
  float acc[9];
#pragma unroll
  for (int e = 0; e < 9; e++) {
    float a = 0.f;
#pragma unroll
    for (int j = 0; j < 8; j++) a = fmaf(xv[j], gws[e][j * 64 + lane], a);
    acc[e] = a;
  }
#pragma unroll
  for (int off = 32; off > 0; off >>= 1) {
#pragma unroll
    for (int e = 0; e < 9; e++) acc[e] += __shfl_down(acc[e], off);
  }
  if (lane == 0) {
    float mx = acc[0];
#pragma unroll
    for (int e = 1; e < 8; e++) mx = fmaxf(mx, acc[e]);
    float p[8], sum = 0.f;
#pragma unroll
    for (int e = 0; e < 8; e++) { p[e] = expf(acc[e] - mx); sum += p[e]; }
    float inv = 1.f / sum;
    int i0 = 0; float b0 = p[0];
#pragma unroll
    for (int e = 1; e < 8; e++) if (p[e] > b0) { b0 = p[e]; i0 = e; }
    int i1 = -1; float b1 = -1.f;
#pragma unroll
    for (int e = 0; e < 8; e++) if (e != i0 && p[e] > b1) { b1 = p[e]; i1 = e; }
#pragma unroll
    for (int e = 0; e < 8; e++) logits[(size_t)t * 8 + e] = acc[e];
    topi[2 * t] = i0; topi[2 * t + 1] = i1;
    topw[2 * t] = b0 * inv; topw[2 * t + 1] = b1 * inv;
    sgate[t] = 1.f / (1.f + expf(-acc[8]));
  }
}

// ---------------- dispatch ----------------
__launch_bounds__(256)
__global__ void dispatch_k(const int* __restrict__ topi, const float* __restrict__ topw,
                           int* __restrict__ counts, int* __restrict__ tok,
                           float* __restrict__ wl, int* __restrict__ pos) {
  __shared__ int lcnt[NE];
  __shared__ int lbase[NE];
  int tid = threadIdx.x;
  if (tid < NE) lcnt[tid] = 0;
  __syncthreads();
  int t = blockIdx.x * 256 + tid;
  int e0 = topi[2 * t], e1 = topi[2 * t + 1];
  float w0 = topw[2 * t], w1 = topw[2 * t + 1];
  int r0 = atomicAdd(&lcnt[e0], 1);
  int r1 = atomicAdd(&lcnt[e1], 1);
  __syncthreads();
  if (tid < NE) lbase[tid] = atomicAdd(&counts[tid], lcnt[tid]);
  __syncthreads();
  int p0 = lbase[e0] + r0;
  int p1 = lbase[e1] + r1;
  if (p0 < CAP) { tok[e0 * CAP + p0] = t; wl[e0 * CAP + p0] = w0; }
  if (p1 < CAP) { tok[e1 * CAP + p1] = t; wl[e1 * CAP + p1] = w1; }
  pos[2 * t]     = (p0 < CAP) ? e0 * CAP + p0 : -1;
  pos[2 * t + 1] = (p1 < CAP) ? e1 * CAP + p1 : -1;
}

// ---------------- fused GEMM1: 16x16x32 MFMA, BM=128 BN=128 dual-acc, BK=64 ----
// Per wave per BK=32 half: 12 ds_read_b128 : 32 MFMA (vs 8:16 at BN=64).
// ~228 regs (128 AGPR) -> 2 blocks/CU; LDS 48KB.
__launch_bounds__(256, 2)
__global__ void gemm1_k(const bf16* __restrict__ X, const int* __restrict__ tokl,
                        const int* __restrict__ counts,
                        const bf16* __restrict__ e1w, const bf16* __restrict__ e3w,
                        const bf16* __restrict__ s1w, const bf16* __restrict__ s3w,
                        bf16* __restrict__ hmoe, bf16* __restrict__ hsh) {
  const bf16 *W1, *W3;
  bf16* Hout;
  const int* tl = nullptr;
  int cnt = 0, m0, n0, N;
  bool gather;
  int y = blockIdx.y;
  if (y < 160) {
    if (blockIdx.x >= IM / 128) return;      // routed N=1024: x<8
    int e = y / 20, mt = y % 20;
    cnt = min(counts[e], CAP);
    if (mt * 128 >= cnt) return;
    gather = true;
    tl = tokl + e * CAP;
    W1 = e1w + (size_t)e * IM * HD;
    W3 = e3w + (size_t)e * IM * HD;
    Hout = hmoe + (size_t)e * CAP * IM;
    N = IM; m0 = mt * 128; n0 = blockIdx.x * 128;
  } else {
    int s = y - 160;                          // 64 m-tiles x 16 n-tiles
    gather = false;
    W1 = s1w; W3 = s3w; Hout = hsh; N = ISH;
    m0 = s * 128; n0 = blockIdx.x * 128;
  }

  __shared__ __align__(16) bf16 As[2][128 * 32];
  __shared__ __align__(16) bf16 B1s[2][128 * 32];
  __shared__ __align__(16) bf16 B3s[2][128 * 32];

  int tid = threadIdx.x;
  int sr = tid >> 2;
  int colb = (tid & 3) * 16;
  int ar0, ar1;
  if (gather) {
    ar0 = tl[min(m0 + sr, cnt - 1)];
    ar1 = tl[min(m0 + 64 + sr, cnt - 1)];
  } else { ar0 = m0 + sr; ar1 = m0 + 64 + sr; }
  const char* apa = (const char*)(X + (size_t)ar0 * HD) + colb;
  const char* apb = (const char*)(X + (size_t)ar1 * HD) + colb;
  const char* bp1a = (const char*)(W1 + (size_t)(n0 + sr) * HD) + colb;
  const char* bp1b = (const char*)(W1 + (size_t)(n0 + 64 + sr) * HD) + colb;
  const char* bp3a = (const char*)(W3 + (size_t)(n0 + sr) * HD) + colb;
  const char* bp3b = (const char*)(W3 + (size_t)(n0 + 64 + sr) * HD) + colb;
  char* lA0a = (char*)&As[0][0] + tid * 16;
  char* lA0b = (char*)&As[1][0] + tid * 16;
  char* lA1a = (char*)&As[0][0] + 4096 + tid * 16;
  char* lA1b = (char*)&As[1][0] + 4096 + tid * 16;
  char* lB1a0 = (char*)&B1s[0][0] + tid * 16;
  char* lB1a1 = (char*)&B1s[0][0] + 4096 + tid * 16;
  char* lB1b0 = (char*)&B1s[1][0] + tid * 16;
  char* lB1b1 = (char*)&B1s[1][0] + 4096 + tid * 16;
  char* lB3a0 = (char*)&B3s[0][0] + tid * 16;
  char* lB3a1 = (char*)&B3s[0][0] + 4096 + tid * 16;
  char* lB3b0 = (char*)&B3s[1][0] + tid * 16;
  char* lB3b1 = (char*)&B3s[1][0] + 4096 + tid * 16;

  int wid = tid >> 6, lane = tid & 63;
  int wm = (wid >> 1) * 64, wn = (wid & 1) * 64;
  int lrow = lane & 15, lq = lane >> 4;

  f32x4 acc1[4][4] = {};
  f32x4 acc3[4][4] = {};

  for (int kb = 0; kb < 1024; kb += 128) {
    __syncthreads();
    gld16(apa + kb, lA0a);       gld16(apa + kb + 64, lA0b);
    gld16(apb + kb, lA1a);       gld16(apb + kb + 64, lA1b);
    gld16(bp1a + kb, lB1a0);     gld16(bp1a + kb + 64, lB1b0);
    gld16(bp1b + kb, lB1a1);     gld16(bp1b + kb + 64, lB1b1);
    gld16(bp3a + kb, lB3a0);     gld16(bp3a + kb + 64, lB3b0);
    gld16(bp3b + kb, lB3a1);     gld16(bp3b + kb + 64, lB3b1);
    __syncthreads();
#pragma unroll
    for (int ks = 0; ks < 2; ks++) {
      bf16x8 a[4], b1[4], b3[4];
#pragma unroll
      for (int i = 0; i < 4; i++)
        a[i] = *(const bf16x8*)&As[ks][(wm + i * 16 + lrow) * 32 + lq * 8];
#pragma unroll
      for (int j = 0; j < 4; j++) {
        b1[j] = *(const bf16x8*)&B1s[ks][(wn + j * 16 + lrow) * 32 + lq * 8];
        b3[j] = *(const bf16x8*)&B3s[ks][(wn + j * 16 + lrow) * 32 + lq * 8];
      }
#pragma unroll
      for (int i = 0; i < 4; i++)
#pragma unroll
        for (int j = 0; j < 4; j++) {
          acc1[i][j] = __builtin_amdgcn_mfma_f32_16x16x32_bf16(a[i], b1[j], acc1[i][j], 0, 0, 0);
          acc3[i][j] = __builtin_amdgcn_mfma_f32_16x16x32_bf16(a[i], b3[j], acc3[i][j], 0, 0, 0);
        }
    }
  }

#pragma unroll
  for (int i = 0; i < 4; i++)
#pragma unroll
    for (int r = 0; r < 4; r++) {
      int row = m0 + wm + i * 16 + lq * 4 + r;
#pragma unroll
      for (int j = 0; j < 4; j++) {
        float v1 = acc1[i][j][r], v3 = acc3[i][j][r];
        float hv = v1 / (1.f + __expf(-v1)) * v3;
        Hout[(size_t)row * N + (n0 + wn + j * 16 + lrow)] = (bf16)hv;
      }
    }
}

// ---------------- fused GEMM2: 16x16x32, m97 shape (R6-verified) ---------------
__launch_bounds__(256, 4)
__global__ void gemm2_k(const bf16* __restrict__ hmoe, const bf16* __restrict__ hsh,
                        const bf16* __restrict__ e2w, const bf16* __restrict__ s2w,
                        const float* __restrict__ wll, const int* __restrict__ counts,
                        bf16* __restrict__ yslot, bf16* __restrict__ ysh) {
  const bf16 *Hin, *W2;
  const float* wlp = nullptr;
  bf16* Yout;
  int cnt = 0, m0, K;
  bool weighted;
  int y = blockIdx.y;
  if (y < 64) {
    weighted = false;
    Hin = hsh; W2 = s2w; Yout = ysh; K = ISH; m0 = y * 128;
  } else {
    int e = (y - 64) / 20, mt = (y - 64) % 20;
    cnt = min(counts[e], CAP);
    if (mt * 128 >= cnt) return;
    weighted = true;
    Hin = hmoe + (size_t)e * CAP * IM;
    W2 = e2w + (size_t)e * HD * IM;
    wlp = wll + e * CAP;
    Yout = yslot + (size_t)e * CAP * HD;
    K = IM; m0 = mt * 128;
  }
  int n0 = blockIdx.x * 128;

  __shared__ __align__(16) bf16 As[128 * 32];
  __shared__ __align__(16) bf16 Bs[128 * 32];

  int tid = threadIdx.x;
  int sr = tid >> 2;
  int colb = (tid & 3) * 16;
  const char* apa = (const char*)(Hin + (size_t)(m0 + sr) * K) + colb;
  const char* apb = (const char*)(Hin + (size_t)(m0 + 64 + sr) * K) + colb;
  const char* bpa = (const char*)(W2 + (size_t)(n0 + sr) * K) + colb;
  const char* bpb = (const char*)(W2 + (size_t)(n0 + 64 + sr) * K) + colb;
  char* lA0 = (char*)As + tid * 16;
  char* lA1 = (char*)As + 4096 + tid * 16;
  char* lB0 = (char*)Bs + tid * 16;
  char* lB1 = (char*)Bs + 4096 + tid * 16;

  int wid = tid >> 6, lane = tid & 63;
  int wm = (wid >> 1) * 64, wn = (wid & 1) * 64;
  int lrow = lane & 15, lq = lane >> 4;

  f32x4 acc[4][4] = {};

  for (int kb = 0; kb < K * 2; kb += 64) {
    __syncthreads();
    gld16(apa + kb, lA0);
    gld16(apb + kb, lA1);
    gld16(bpa + kb, lB0);
    gld16(bpb + kb, lB1);
    __syncthreads();
    bf16x8 a[4], b[4];
#pragma unroll
    for (int i = 0; i < 4; i++) {
      a[i] = *(const bf16x8*)&As[(wm + i * 16 + lrow) * 32 + lq * 8];
      b[i] = *(const bf16x8*)&Bs[(wn + i * 16 + lrow) * 32 + lq * 8];
    }
#pragma unroll
    for (int i = 0; i < 4; i++)
#pragma unroll
      for (int j = 0; j < 4; j++)
        acc[i][j] = __builtin_amdgcn_mfma_f32_16x16x32_bf16(a[i], b[j], acc[i][j], 0, 0, 0);
  }

#pragma unroll
  for (int i = 0; i < 4; i++)
#pragma unroll
    for (int r = 0; r < 4; r++) {
      int row = m0 + wm + i * 16 + lq * 4 + r;
      float w = weighted ? ((row < cnt) ? wlp[row] : 0.f) : 1.f;
      bf16* op = Yout + (size_t)row * HD;
#pragma unroll
      for (int j = 0; j < 4; j++)
        op[n0 + wn + j * 16 + lrow] = (bf16)(w * acc[i][j][r]);
    }
}

// ---------------- combine ----------------
__launch_bounds__(256)
__global__ void combine_k(const bf16* __restrict__ yslot, const bf16* __restrict__ ysh,
                          const int* __restrict__ pos, const float* __restrict__ sgate,
                          float* __restrict__ out) {
  int wave = threadIdx.x >> 6, lane = threadIdx.x & 63;
  int t = blockIdx.x * 4 + wave;
  int p0 = pos[2 * t], p1 = pos[2 * t + 1];
  float g = sgate[t];
  int col = lane * 8;
  float acc[8];
  {
    const bf16x8 s = *(const bf16x8*)(ysh + (size_t)t * HD + col);
#pragma unroll
    for (int i = 0; i < 8; i++) acc[i] = g * (float)s[i];
  }
  if (p0 >= 0) {
    const bf16x8 v = *(const bf16x8*)(yslot + (size_t)p0 * HD + col);
#pragma unroll
    for (int i = 0; i < 8; i++) acc[i] += (float)v[i];
  }
  if (p1 >= 0) {
    const bf16x8 v = *(const bf16x8*)(yslot + (size_t)p1 * HD + col);
#pragma unroll
    for (int i = 0; i < 8; i++) acc[i] += (float)v[i];
  }
  float* op = out + (size_t)t * HD + col;
#pragma unroll
  for (int i = 0; i < 8; i++) op[i] = acc[i];
}

// ---------------- launch ----------------
extern "C" void kernel_launch(void* const* d_in, const int* in_sizes, int n_in,
                              void* d_out, int out_size, void* d_ws, size_t ws_size,
                              hipStream_t stream) {
  const float* x   = (const float*)d_in[0];
  const float* gw  = (const float*)d_in[1];
  const float* ew1 = (const float*)d_in[2];
  const float* ew2 = (const float*)d_in[3];
  const float* ew3 = (const float*)d_in[4];
  const float* sw1 = (const float*)d_in[5];
  const float* sw2 = (const float*)d_in[6];
  const float* sw3 = (const float*)d_in[7];
  const float* sgw = (const float*)d_in[8];
  float* out = (float*)d_out;
  float* logits = out + (size_t)TOKENS * HD;

  char* w = (char*)d_ws;
  bf16* xb  = (bf16*)w; w += (size_t)TOKENS * HD * 2;
  bf16* e1b = (bf16*)w; w += (size_t)NE * IM * HD * 2;
  bf16* e3b = (bf16*)w; w += (size_t)NE * IM * HD * 2;
  bf16* s1b = (bf16*)w; w += (size_t)ISH * HD * 2;
  bf16* s3b = (bf16*)w; w += (size_t)ISH * HD * 2;
  bf16* e2b = (bf16*)w; w += (size_t)NE * HD * IM * 2;
  bf16* s2b = (bf16*)w; w += (size_t)HD * ISH * 2;
  float* sgate = (float*)w; w += TOKENS * 4;
  int*   topi  = (int*)w;   w += TOKENS * 2 * 4;
  float* topw  = (float*)w; w += TOKENS * 2 * 4;
  int*   counts = (int*)w;  w += 256;
  int*   tok   = (int*)w;   w += NE * CAP * 4;
  float* wl    = (float*)w; w += NE * CAP * 4;
  int*   pos   = (int*)w;   w += TOKENS * 2 * 4;
  bf16* hmoe = (bf16*)w; w += (size_t)NE * CAP * IM * 2;
  bf16* hsh  = (bf16*)w; w += (size_t)TOKENS * ISH * 2;
  bf16* yslot = xb;
  bf16* ysh   = (bf16*)((char*)xb + (size_t)NE * CAP * HD * 2);

  hipLaunchKernelGGL(router_cvt_k, dim3(RT_BLOCKS + CVT_BLOCKS), dim3(256), 0, stream,
                     x, gw, sgw, logits, sgate, topi, topw, counts, xb,
                     ew1, ew3, sw1, sw3, ew2, sw2, e1b);
  hipLaunchKernelGGL(dispatch_k, dim3(TOKENS / 256), dim3(256), 0, stream,
                     topi, topw, counts, tok, wl, pos);
  hipLaunchKernelGGL(gemm1_k, dim3(16, 160 + 64), dim3(256), 0, stream,
                     xb, tok, counts, e1b, e3b, s1b, s3b, hmoe, hsh);
  hipLaunchKernelGGL(gemm2_k, dim3(4, 64 + 160), dim3(256), 0, stream,
                     hmoe, hsh, e2b, s2b, wl, counts, yslot, ysh);
  hipLaunchKernelGGL(combine_k, dim3(TOKENS / 4), dim3(256), 0, stream,
                     yslot, ysh, pos, sgate, out);
}

// Round 9
// 270.200 us; speedup vs baseline: 1.1667x; 1.1667x over previous
//
#include <hip/hip_runtime.h>
#include <hip/hip_bf16.h>
#include <stdint.h>
#include <math.h>

typedef __bf16 bf16;
typedef bf16 bf16x8 __attribute__((ext_vector_type(8)));
typedef bf16 bf16x4 __attribute__((ext_vector_type(4)));
typedef float f32x4 __attribute__((ext_vector_type(4)));
typedef unsigned int u32;

#define TOKENS 8192
#define HD 512
#define NE 8
#define IM 1024
#define ISH 2048
#define CAP 2560   // per-expert slot capacity; mean load 2048, sigma~42

__device__ __forceinline__ void gld16(const void* g, void* l) {
  __builtin_amdgcn_global_load_lds(
      (const __attribute__((address_space(1))) u32*)g,
      (__attribute__((address_space(3))) u32*)l, 16, 0, 0);
}

// ---------------- fused router + weight-convert (one dispatch) ----------------
#define RT_BLOCKS (TOKENS / 4)
#define CVT_BLOCKS 3840
#define CVT_STRIDE (CVT_BLOCKS * 256)   // F4_TOT = 4 * CVT_STRIDE exactly
#define F4_E  (NE * IM * HD / 4)
#define F4_S  (ISH * HD / 4)
#define F4_C1 (F4_E)
#define F4_C2 (F4_C1 + F4_E)
#define F4_C3 (F4_C2 + F4_S)
#define F4_C4 (F4_C3 + F4_S)
#define F4_C5 (F4_C4 + F4_E)
#define F4_TOT (F4_C5 + F4_S)

__launch_bounds__(256)
__global__ void router_cvt_k(const float* __restrict__ x, const float* __restrict__ gw,
                             const float* __restrict__ sgw, float* __restrict__ logits,
                             float* __restrict__ sgate, int* __restrict__ topi,
                             float* __restrict__ topw, int* __restrict__ counts,
                             bf16* __restrict__ xb,
                             const float* __restrict__ e1, const float* __restrict__ e3,
                             const float* __restrict__ s1, const float* __restrict__ s3,
                             const float* __restrict__ e2, const float* __restrict__ s2,
                             bf16* __restrict__ wdst) {
  if (blockIdx.x >= RT_BLOCKS) {
    int idx = (blockIdx.x - RT_BLOCKS) * 256 + threadIdx.x;
#pragma unroll
    for (int it = 0; it < 4; it++, idx += CVT_STRIDE) {
      const float* s; int off;
      if (idx < F4_C1)      { s = e1; off = idx; }
      else if (idx < F4_C2) { s = e3; off = idx - F4_C1; }
      else if (idx < F4_C3) { s = s1; off = idx - F4_C2; }
      else if (idx < F4_C4) { s = s3; off = idx - F4_C3; }
      else if (idx < F4_C5) { s = e2; off = idx - F4_C4; }
      else                  { s = s2; off = idx - F4_C5; }
      const float4 v = ((const float4*)s)[off];
      bf16x4 o;
      o.x = (bf16)v.x; o.y = (bf16)v.y; o.z = (bf16)v.z; o.w = (bf16)v.w;
      ((bf16x4*)wdst)[idx] = o;
    }
    return;
  }
  if (blockIdx.x == 0 && threadIdx.x < NE) counts[threadIdx.x] = 0;
  // gate weights bank-permuted: col c -> (c&7)*64 + c>>3, so gws[e][j*64+lane]
  // is the weight for column lane*8+j (x loaded contiguous-per-lane)
  __shared__ float gws[9][512];
  for (int i = threadIdx.x; i < 9 * 512; i += 256) {
    int r = i >> 9, c = i & 511;
    float v = (r < 8) ? gw[i] : sgw[c];
    gws[r][((c & 7) << 6) | (c >> 3)] = v;
  }
  __syncthreads();
  int wave = threadIdx.x >> 6, lane = threadIdx.x & 63;
  int t = blockIdx.x * 4 + wave;
  const float* xp = x + (size_t)t * HD + lane * 8;
  float4 va = *(const float4*)xp;
  float4 vb = *(const float4*)(xp + 4);
  float xv[8] = {va.x, va.y, va.z, va.w, vb.x, vb.y, vb.z, vb.w};
  {
    bf16x8 xo;
#pragma unroll
    for (int j = 0; j < 8; j++) xo[j] = (bf16)xv[j];
    *(bf16x8*)(xb + (size_t)t * HD + lane * 8) = xo;
  }
  float acc[9];
#pragma unroll
  for (int e = 0; e < 9; e++) {
    float a = 0.f;
#pragma unroll
    for (int j = 0; j < 8; j++) a = fmaf(xv[j], gws[e][j * 64 + lane], a);
    acc[e] = a;
  }
#pragma unroll
  for (int off = 32; off > 0; off >>= 1) {
#pragma unroll
    for (int e = 0; e < 9; e++) acc[e] += __shfl_down(acc[e], off);
  }
  if (lane == 0) {
    float mx = acc[0];
#pragma unroll
    for (int e = 1; e < 8; e++) mx = fmaxf(mx, acc[e]);
    float p[8], sum = 0.f;
#pragma unroll
    for (int e = 0; e < 8; e++) { p[e] = expf(acc[e] - mx); sum += p[e]; }
    float inv = 1.f / sum;
    int i0 = 0; float b0 = p[0];
#pragma unroll
    for (int e = 1; e < 8; e++) if (p[e] > b0) { b0 = p[e]; i0 = e; }
    int i1 = -1; float b1 = -1.f;
#pragma unroll
    for (int e = 0; e < 8; e++) if (e != i0 && p[e] > b1) { b1 = p[e]; i1 = e; }
#pragma unroll
    for (int e = 0; e < 8; e++) logits[(size_t)t * 8 + e] = acc[e];
    topi[2 * t] = i0; topi[2 * t + 1] = i1;
    topw[2 * t] = b0 * inv; topw[2 * t + 1] = b1 * inv;
    sgate[t] = 1.f / (1.f + expf(-acc[8]));
  }
}

// ---------------- dispatch ----------------
__launch_bounds__(256)
__global__ void dispatch_k(const int* __restrict__ topi, const float* __restrict__ topw,
                           int* __restrict__ counts, int* __restrict__ tok,
                           float* __restrict__ wl, int* __restrict__ pos) {
  __shared__ int lcnt[NE];
  __shared__ int lbase[NE];
  int tid = threadIdx.x;
  if (tid < NE) lcnt[tid] = 0;
  __syncthreads();
  int t = blockIdx.x * 256 + tid;
  int e0 = topi[2 * t], e1 = topi[2 * t + 1];
  float w0 = topw[2 * t], w1 = topw[2 * t + 1];
  int r0 = atomicAdd(&lcnt[e0], 1);
  int r1 = atomicAdd(&lcnt[e1], 1);
  __syncthreads();
  if (tid < NE) lbase[tid] = atomicAdd(&counts[tid], lcnt[tid]);
  __syncthreads();
  int p0 = lbase[e0] + r0;
  int p1 = lbase[e1] + r1;
  if (p0 < CAP) { tok[e0 * CAP + p0] = t; wl[e0 * CAP + p0] = w0; }
  if (p1 < CAP) { tok[e1 * CAP + p1] = t; wl[e1 * CAP + p1] = w1; }
  pos[2 * t]     = (p0 < CAP) ? e0 * CAP + p0 : -1;
  pos[2 * t + 1] = (p1 < CAP) ? e1 * CAP + p1 : -1;
}

// ---------------- fused GEMM1 (R6 config: 16x16x32, BM=128 BN=64 dual, BK=64) --
// Best known operating point: ~64 VGPR + 64 AGPR, 32KB LDS, ~3 blocks/CU,
// 80 us / 857 TF. BN=128 (R8) and 32x32 shape (R7) both regressed — do not
// re-raise tile without a new occupancy lever.
__launch_bounds__(256, 4)
__global__ void gemm1_k(const bf16* __restrict__ X, const int* __restrict__ tokl,
                        const int* __restrict__ counts,
                        const bf16* __restrict__ e1w, const bf16* __restrict__ e3w,
                        const bf16* __restrict__ s1w, const bf16* __restrict__ s3w,
                        bf16* __restrict__ hmoe, bf16* __restrict__ hsh) {
  const bf16 *W1, *W3;
  bf16* Hout;
  const int* tl = nullptr;
  int cnt = 0, m0, n0, N;
  bool gather;
  int y = blockIdx.y;
  if (y < 160) {
    int e = y / 20, mt = y % 20;
    cnt = min(counts[e], CAP);
    if (mt * 128 >= cnt) return;
    gather = true;
    tl = tokl + e * CAP;
    W1 = e1w + (size_t)e * IM * HD;
    W3 = e3w + (size_t)e * IM * HD;
    Hout = hmoe + (size_t)e * CAP * IM;
    N = IM; m0 = mt * 128; n0 = blockIdx.x * 64;
  } else {
    int s = y - 160;
    gather = false;
    W1 = s1w; W3 = s3w; Hout = hsh; N = ISH;
    m0 = (s >> 1) * 128;
    n0 = ((s & 1) * 16 + blockIdx.x) * 64;
  }

  __shared__ __align__(16) bf16 As[2][128 * 32];
  __shared__ __align__(16) bf16 B1s[2][64 * 32];
  __shared__ __align__(16) bf16 B3s[2][64 * 32];

  int tid = threadIdx.x;
  int sr = tid >> 2;
  int colb = (tid & 3) * 16;
  int ar0, ar1;
  if (gather) {
    ar0 = tl[min(m0 + sr, cnt - 1)];
    ar1 = tl[min(m0 + 64 + sr, cnt - 1)];
  } else { ar0 = m0 + sr; ar1 = m0 + 64 + sr; }
  const char* apa = (const char*)(X + (size_t)ar0 * HD) + colb;
  const char* apb = (const char*)(X + (size_t)ar1 * HD) + colb;
  const char* bp1 = (const char*)(W1 + (size_t)(n0 + sr) * HD) + colb;
  const char* bp3 = (const char*)(W3 + (size_t)(n0 + sr) * HD) + colb;
  char* lA0a = (char*)&As[0][0] + tid * 16;
  char* lA0b = (char*)&As[1][0] + tid * 16;
  char* lA1a = (char*)&As[0][0] + 4096 + tid * 16;
  char* lA1b = (char*)&As[1][0] + 4096 + tid * 16;
  char* lB1a = (char*)&B1s[0][0] + tid * 16;
  char* lB1b = (char*)&B1s[1][0] + tid * 16;
  char* lB3a = (char*)&B3s[0][0] + tid * 16;
  char* lB3b = (char*)&B3s[1][0] + tid * 16;

  int wid = tid >> 6, lane = tid & 63;
  int wm = (wid >> 1) * 64, wn = (wid & 1) * 32;
  int lrow = lane & 15, lq = lane >> 4;

  f32x4 acc1[4][2] = {};
  f32x4 acc3[4][2] = {};

  for (int kb = 0; kb < 1024; kb += 128) {
    __syncthreads();
    gld16(apa + kb, lA0a);      gld16(apa + kb + 64, lA0b);
    gld16(apb + kb, lA1a);      gld16(apb + kb + 64, lA1b);
    gld16(bp1 + kb, lB1a);      gld16(bp1 + kb + 64, lB1b);
    gld16(bp3 + kb, lB3a);      gld16(bp3 + kb + 64, lB3b);
    __syncthreads();
#pragma unroll
    for (int ks = 0; ks < 2; ks++) {
      bf16x8 a[4], b1[2], b3[2];
#pragma unroll
      for (int i = 0; i < 4; i++)
        a[i] = *(const bf16x8*)&As[ks][(wm + i * 16 + lrow) * 32 + lq * 8];
#pragma unroll
      for (int j = 0; j < 2; j++) {
        b1[j] = *(const bf16x8*)&B1s[ks][(wn + j * 16 + lrow) * 32 + lq * 8];
        b3[j] = *(const bf16x8*)&B3s[ks][(wn + j * 16 + lrow) * 32 + lq * 8];
      }
#pragma unroll
      for (int i = 0; i < 4; i++)
#pragma unroll
        for (int j = 0; j < 2; j++) {
          acc1[i][j] = __builtin_amdgcn_mfma_f32_16x16x32_bf16(a[i], b1[j], acc1[i][j], 0, 0, 0);
          acc3[i][j] = __builtin_amdgcn_mfma_f32_16x16x32_bf16(a[i], b3[j], acc3[i][j], 0, 0, 0);
        }
    }
  }

#pragma unroll
  for (int i = 0; i < 4; i++)
#pragma unroll
    for (int r = 0; r < 4; r++) {
      int row = m0 + wm + i * 16 + lq * 4 + r;
#pragma unroll
      for (int j = 0; j < 2; j++) {
        float v1 = acc1[i][j][r], v3 = acc3[i][j][r];
        float hv = v1 / (1.f + __expf(-v1)) * v3;
        Hout[(size_t)row * N + (n0 + wn + j * 16 + lrow)] = (bf16)hv;
      }
    }
}

// ---------------- fused GEMM2: 16x16x32, BM=BN=128, BK=64 (two 32-col halves) --
// Shared tiles FIRST (K=2048, LPT order), routed after. 32KB LDS -> 4 blocks/CU.
__launch_bounds__(256, 4)
__global__ void gemm2_k(const bf16* __restrict__ hmoe, const bf16* __restrict__ hsh,
                        const bf16* __restrict__ e2w, const bf16* __restrict__ s2w,
                        const float* __restrict__ wll, const int* __restrict__ counts,
                        bf16* __restrict__ yslot, bf16* __restrict__ ysh) {
  const bf16 *Hin, *W2;
  const float* wlp = nullptr;
  bf16* Yout;
  int cnt = 0, m0, K;
  bool weighted;
  int y = blockIdx.y;
  if (y < 64) {
    weighted = false;
    Hin = hsh; W2 = s2w; Yout = ysh; K = ISH; m0 = y * 128;
  } else {
    int e = (y - 64) / 20, mt = (y - 64) % 20;
    cnt = min(counts[e], CAP);
    if (mt * 128 >= cnt) return;
    weighted = true;
    Hin = hmoe + (size_t)e * CAP * IM;
    W2 = e2w + (size_t)e * HD * IM;
    wlp = wll + e * CAP;
    Yout = yslot + (size_t)e * CAP * HD;
    K = IM; m0 = mt * 128;
  }
  int n0 = blockIdx.x * 128;

  __shared__ __align__(16) bf16 As[2][128 * 32];
  __shared__ __align__(16) bf16 Bs[2][128 * 32];

  int tid = threadIdx.x;
  int sr = tid >> 2;
  int colb = (tid & 3) * 16;
  const char* apa = (const char*)(Hin + (size_t)(m0 + sr) * K) + colb;
  const char* apb = (const char*)(Hin + (size_t)(m0 + 64 + sr) * K) + colb;
  const char* bpa = (const char*)(W2 + (size_t)(n0 + sr) * K) + colb;
  const char* bpb = (const char*)(W2 + (size_t)(n0 + 64 + sr) * K) + colb;
  char* lA0a = (char*)&As[0][0] + tid * 16;
  char* lA0b = (char*)&As[1][0] + tid * 16;
  char* lA1a = (char*)&As[0][0] + 4096 + tid * 16;
  char* lA1b = (char*)&As[1][0] + 4096 + tid * 16;
  char* lB0a = (char*)&Bs[0][0] + tid * 16;
  char* lB0b = (char*)&Bs[1][0] + tid * 16;
  char* lB1a = (char*)&Bs[0][0] + 4096 + tid * 16;
  char* lB1b = (char*)&Bs[1][0] + 4096 + tid * 16;

  int wid = tid >> 6, lane = tid & 63;
  int wm = (wid >> 1) * 64, wn = (wid & 1) * 64;
  int lrow = lane & 15, lq = lane >> 4;

  f32x4 acc[4][4] = {};

  for (int kb = 0; kb < K * 2; kb += 128) {
    __syncthreads();
    gld16(apa + kb, lA0a);      gld16(apa + kb + 64, lA0b);
    gld16(apb + kb, lA1a);      gld16(apb + kb + 64, lA1b);
    gld16(bpa + kb, lB0a);      gld16(bpa + kb + 64, lB0b);
    gld16(bpb + kb, lB1a);      gld16(bpb + kb + 64, lB1b);
    __syncthreads();
#pragma unroll
    for (int ks = 0; ks < 2; ks++) {
      bf16x8 a[4], b[4];
#pragma unroll
      for (int i = 0; i < 4; i++) {
        a[i] = *(const bf16x8*)&As[ks][(wm + i * 16 + lrow) * 32 + lq * 8];
        b[i] = *(const bf16x8*)&Bs[ks][(wn + i * 16 + lrow) * 32 + lq * 8];
      }
#pragma unroll
      for (int i = 0; i < 4; i++)
#pragma unroll
        for (int j = 0; j < 4; j++)
          acc[i][j] = __builtin_amdgcn_mfma_f32_16x16x32_bf16(a[i], b[j], acc[i][j], 0, 0, 0);
    }
  }

#pragma unroll
  for (int i = 0; i < 4; i++)
#pragma unroll
    for (int r = 0; r < 4; r++) {
      int row = m0 + wm + i * 16 + lq * 4 + r;
      float w = weighted ? ((row < cnt) ? wlp[row] : 0.f) : 1.f;
      bf16* op = Yout + (size_t)row * HD;
#pragma unroll
      for (int j = 0; j < 4; j++)
        op[n0 + wn + j * 16 + lrow] = (bf16)(w * acc[i][j][r]);
    }
}

// ---------------- combine: out[t] = y[pos0] + y[pos1] + sgate*ysh[t] -----------
__launch_bounds__(256)
__global__ void combine_k(const bf16* __restrict__ yslot, const bf16* __restrict__ ysh,
                          const int* __restrict__ pos, const float* __restrict__ sgate,
                          float* __restrict__ out) {
  int wave = threadIdx.x >> 6, lane = threadIdx.x & 63;
  int t = blockIdx.x * 4 + wave;
  int p0 = pos[2 * t], p1 = pos[2 * t + 1];
  float g = sgate[t];
  int col = lane * 8;
  float acc[8];
  {
    const bf16x8 s = *(const bf16x8*)(ysh + (size_t)t * HD + col);
#pragma unroll
    for (int i = 0; i < 8; i++) acc[i] = g * (float)s[i];
  }
  if (p0 >= 0) {
    const bf16x8 v = *(const bf16x8*)(yslot + (size_t)p0 * HD + col);
#pragma unroll
    for (int i = 0; i < 8; i++) acc[i] += (float)v[i];
  }
  if (p1 >= 0) {
    const bf16x8 v = *(const bf16x8*)(yslot + (size_t)p1 * HD + col);
#pragma unroll
    for (int i = 0; i < 8; i++) acc[i] += (float)v[i];
  }
  float* op = out + (size_t)t * HD + col;
#pragma unroll
  for (int i = 0; i < 8; i++) op[i] = acc[i];
}

// ---------------- launch ----------------
extern "C" void kernel_launch(void* const* d_in, const int* in_sizes, int n_in,
                              void* d_out, int out_size, void* d_ws, size_t ws_size,
                              hipStream_t stream) {
  const float* x   = (const float*)d_in[0];
  const float* gw  = (const float*)d_in[1];
  const float* ew1 = (const float*)d_in[2];
  const float* ew2 = (const float*)d_in[3];
  const float* ew3 = (const float*)d_in[4];
  const float* sw1 = (const float*)d_in[5];
  const float* sw2 = (const float*)d_in[6];
  const float* sw3 = (const float*)d_in[7];
  const float* sgw = (const float*)d_in[8];
  float* out = (float*)d_out;
  float* logits = out + (size_t)TOKENS * HD;

  // bf16 staging layout: xb..s3b are dead after gemm1 and are reused as
  // yslot/ysh (29,360,128 B, exact fit); e2b/s2b stay live through gemm2.
  char* w = (char*)d_ws;
  bf16* xb  = (bf16*)w; w += (size_t)TOKENS * HD * 2;
  bf16* e1b = (bf16*)w; w += (size_t)NE * IM * HD * 2;
  bf16* e3b = (bf16*)w; w += (size_t)NE * IM * HD * 2;
  bf16* s1b = (bf16*)w; w += (size_t)ISH * HD * 2;
  bf16* s3b = (bf16*)w; w += (size_t)ISH * HD * 2;
  bf16* e2b = (bf16*)w; w += (size_t)NE * HD * IM * 2;
  bf16* s2b = (bf16*)w; w += (size_t)HD * ISH * 2;
  float* sgate = (float*)w; w += TOKENS * 4;
  int*   topi  = (int*)w;   w += TOKENS * 2 * 4;
  float* topw  = (float*)w; w += TOKENS * 2 * 4;
  int*   counts = (int*)w;  w += 256;
  int*   tok   = (int*)w;   w += NE * CAP * 4;
  float* wl    = (float*)w; w += NE * CAP * 4;
  int*   pos   = (int*)w;   w += TOKENS * 2 * 4;
  bf16* hmoe = (bf16*)w; w += (size_t)NE * CAP * IM * 2;
  bf16* hsh  = (bf16*)w; w += (size_t)TOKENS * ISH * 2;
  bf16* yslot = xb;
  bf16* ysh   = (bf16*)((char*)xb + (size_t)NE * CAP * HD * 2);

  hipLaunchKernelGGL(router_cvt_k, dim3(RT_BLOCKS + CVT_BLOCKS), dim3(256), 0, stream,
                     x, gw, sgw, logits, sgate, topi, topw, counts, xb,
                     ew1, ew3, sw1, sw3, ew2, sw2, e1b);
  hipLaunchKernelGGL(dispatch_k, dim3(TOKENS / 256), dim3(256), 0, stream,
                     topi, topw, counts, tok, wl, pos);
  hipLaunchKernelGGL(gemm1_k, dim3(16, 160 + 128), dim3(256), 0, stream,
                     xb, tok, counts, e1b, e3b, s1b, s3b, hmoe, hsh);
  hipLaunchKernelGGL(gemm2_k, dim3(4, 64 + 160), dim3(256), 0, stream,
                     hmoe, hsh, e2b, s2b, wl, counts, yslot, ysh);
  hipLaunchKernelGGL(combine_k, dim3(TOKENS / 4), dim3(256), 0, stream,
                     yslot, ysh, pos, sgate, out);
}